// Round 2
// baseline (2094.988 us; speedup 1.0000x reference)
//
#include <hip/hip_runtime.h>

#define N_USER_C 100000
#define N_NODES_C 150000
#define EMB_C 64

// x0 = concat(user_emb, item_emb) (vectorized float4).
// Optionally: a = copy of x0 (copy_a=1) or zero; b,c zeroed if non-null.
__global__ __launch_bounds__(256) void fill_kernel(
        const float4* __restrict__ ue, const float4* __restrict__ ie,
        float4* __restrict__ x0, float4* __restrict__ a,
        float4* __restrict__ b, float4* __restrict__ c,
        long long u4, long long t4, int copy_a) {
    long long i = (long long)blockIdx.x * blockDim.x + threadIdx.x;
    if (i >= t4) return;
    float4 v = (i < u4) ? ue[i] : ie[i - u4];
    float4 z = make_float4(0.f, 0.f, 0.f, 0.f);
    x0[i] = v;
    if (a) a[i] = copy_a ? v : z;
    if (b) b[i] = z;
    if (c) c[i] = z;
}

// One wave per edge, one lane per embedding dim.
// xout[rows[e]][d] += vals[e] * xin[cols[e]][d]
__global__ __launch_bounds__(256) void spmm_kernel(
        const float* __restrict__ vals, const int* __restrict__ rows,
        const int* __restrict__ cols, const float* __restrict__ xin,
        float* __restrict__ xout, int nnz) {
    long long gid = (long long)blockIdx.x * blockDim.x + threadIdx.x;
    int e = (int)(gid >> 6);
    int d = (int)(gid & 63);
    if (e >= nnz) return;
    int r = rows[e];      // wave-uniform address -> single request
    int c = cols[e];
    float v = vals[e];
    float contrib = v * xin[(long long)c * EMB_C + d];
    unsafeAtomicAdd(&xout[(long long)r * EMB_C + d], contrib);
}

// acc += src; optionally zero `tozero` (next layer's target) in the same pass.
__global__ __launch_bounds__(256) void acczero_kernel(
        float4* __restrict__ acc, const float4* __restrict__ src,
        float4* __restrict__ tozero, long long n4) {
    long long i = (long long)blockIdx.x * blockDim.x + threadIdx.x;
    if (i >= n4) return;
    float4 a = acc[i], s = src[i];
    a.x += s.x; a.y += s.y; a.z += s.z; a.w += s.w;
    acc[i] = a;
    if (tozero) tozero[i] = make_float4(0.f, 0.f, 0.f, 0.f);
}

// out[gid] = scale * (p0[idx] + p1[idx] + p2[idx] + p3[idx]) at gathered rows.
__global__ __launch_bounds__(256) void gather_kernel(
        const float* __restrict__ p0, const float* __restrict__ p1,
        const float* __restrict__ p2, const float* __restrict__ p3,
        const int* __restrict__ users, const int* __restrict__ pos,
        const int* __restrict__ neg, float* __restrict__ out,
        int batch, float scale) {
    long long gid = (long long)blockIdx.x * blockDim.x + threadIdx.x;
    long long per = (long long)batch * EMB_C;
    if (gid >= 3 * per) return;
    int which = (int)(gid / per);
    long long rem = gid - (long long)which * per;
    int b = (int)(rem >> 6);
    int d = (int)(rem & 63);
    long long row;
    if (which == 0)      row = users[b];
    else if (which == 1) row = (long long)N_USER_C + pos[b];
    else                 row = (long long)N_USER_C + neg[b];
    long long idx = row * EMB_C + d;
    out[gid] = scale * (p0[idx] + p1[idx] + p2[idx] + p3[idx]);
}

extern "C" void kernel_launch(void* const* d_in, const int* in_sizes, int n_in,
                              void* d_out, int out_size, void* d_ws, size_t ws_size,
                              hipStream_t stream) {
    const float* ue    = (const float*)d_in[0];
    const float* ie    = (const float*)d_in[1];
    const float* vals  = (const float*)d_in[2];
    const int*   rows  = (const int*)d_in[3];
    const int*   cols  = (const int*)d_in[4];
    const int*   users = (const int*)d_in[5];
    const int*   pos   = (const int*)d_in[6];
    const int*   neg   = (const int*)d_in[7];
    float* out = (float*)d_out;

    const int nnz   = in_sizes[2];
    const int batch = in_sizes[5];
    const long long uelems = (long long)in_sizes[0];           // N_USER*EMB
    const long long total  = uelems + (long long)in_sizes[1];  // N_NODES*EMB
    const long long u4 = uelems / 4, t4 = total / 4;

    const int threads = 256;
    const long long fill_blocks  = (t4 + threads - 1) / threads;
    const long long spmm_blocks  = ((long long)nnz * EMB_C + threads - 1) / threads;
    const long long gath_blocks  = (3LL * batch * EMB_C + threads - 1) / threads;

    float* w = (float*)d_ws;

    if (ws_size >= (size_t)(4 * total) * sizeof(float)) {
        // ---- 4-buffer layout: x0 -> x1 -> x2 -> x3, gather sums all four ----
        float* x0 = w;
        float* x1 = x0 + total;
        float* x2 = x1 + total;
        float* x3 = x2 + total;
        fill_kernel<<<(int)fill_blocks, threads, 0, stream>>>(
            (const float4*)ue, (const float4*)ie,
            (float4*)x0, (float4*)x1, (float4*)x2, (float4*)x3, u4, t4, 0);
        spmm_kernel<<<(int)spmm_blocks, threads, 0, stream>>>(vals, rows, cols, x0, x1, nnz);
        spmm_kernel<<<(int)spmm_blocks, threads, 0, stream>>>(vals, rows, cols, x1, x2, nnz);
        spmm_kernel<<<(int)spmm_blocks, threads, 0, stream>>>(vals, rows, cols, x2, x3, nnz);
        gather_kernel<<<(int)gath_blocks, threads, 0, stream>>>(
            x0, x1, x2, x3, users, pos, neg, out, batch, 0.25f);
    } else {
        // ---- 3-buffer fallback: cur/nxt ping-pong + acc ----
        float* cur = w;
        float* nxt = cur + total;
        float* acc = nxt + total;
        fill_kernel<<<(int)fill_blocks, threads, 0, stream>>>(
            (const float4*)ue, (const float4*)ie,
            (float4*)cur, (float4*)acc, (float4*)nxt, nullptr, u4, t4, 1);
        for (int l = 0; l < 3; ++l) {
            spmm_kernel<<<(int)spmm_blocks, threads, 0, stream>>>(vals, rows, cols, cur, nxt, nnz);
            float4* tz = (l < 2) ? (float4*)cur : nullptr;  // zero next target
            acczero_kernel<<<(int)fill_blocks, threads, 0, stream>>>(
                (float4*)acc, (const float4*)nxt, tz, t4);
            float* t = cur; cur = nxt; nxt = t;
        }
        gather_kernel<<<(int)gath_blocks, threads, 0, stream>>>(
            acc, acc, acc, acc, users, pos, neg, out, batch, 0.0625f);
    }
}

// Round 5
// 722.156 us; speedup vs baseline: 2.9010x; 2.9010x over previous
//
#include <hip/hip_runtime.h>

#define EMB_C 64
#define N_USER_C 100000

// ============================ CSR path kernels ============================

// x0 = concat(user_emb, item_emb); optionally acc = x0; zero cnt+bs region.
__global__ __launch_bounds__(256) void fill_csr_kernel(
        const float4* __restrict__ ue, const float4* __restrict__ ie,
        float4* __restrict__ x0, float4* __restrict__ acc,
        int4* __restrict__ zint, long long u4, long long t4, long long z4) {
    long long i = (long long)blockIdx.x * blockDim.x + threadIdx.x;
    if (i < t4) {
        float4 v = (i < u4) ? ue[i] : ie[i - u4];
        x0[i] = v;
        if (acc) acc[i] = v;
    }
    if (i < z4) zint[i] = make_int4(0, 0, 0, 0);
}

__global__ __launch_bounds__(256) void hist_kernel(
        const int* __restrict__ rows, int* __restrict__ cnt, int nnz) {
    int e = blockIdx.x * 256 + threadIdx.x;
    if (e < nnz) atomicAdd(&cnt[rows[e]], 1);
}

// Block-wise inclusive scan of cnt -> rp[i+1]; block totals -> bsum.
__global__ __launch_bounds__(256) void scan1_kernel(
        const int* __restrict__ cnt, int* __restrict__ rp,
        int* __restrict__ bsum, int n) {
    __shared__ int sh[256];
    int i = blockIdx.x * 256 + threadIdx.x;
    int v = (i < n) ? cnt[i] : 0;
    sh[threadIdx.x] = v;
    __syncthreads();
    for (int off = 1; off < 256; off <<= 1) {
        int t = (threadIdx.x >= off) ? sh[threadIdx.x - off] : 0;
        __syncthreads();
        sh[threadIdx.x] += t;
        __syncthreads();
    }
    if (i < n) rp[i + 1] = sh[threadIdx.x];
    if (threadIdx.x == 255) bsum[blockIdx.x] = sh[255];
}

// Exclusive scan of bsum (nb <= 1024), single block.
__global__ __launch_bounds__(1024) void scan2_kernel(int* __restrict__ bsum, int nb) {
    __shared__ int sh[1024];
    int v = (threadIdx.x < nb) ? bsum[threadIdx.x] : 0;
    sh[threadIdx.x] = v;
    __syncthreads();
    for (int off = 1; off < 1024; off <<= 1) {
        int t = (threadIdx.x >= off) ? sh[threadIdx.x - off] : 0;
        __syncthreads();
        sh[threadIdx.x] += t;
        __syncthreads();
    }
    if (threadIdx.x < nb) bsum[threadIdx.x] = (threadIdx.x == 0) ? 0 : sh[threadIdx.x - 1];
}

// rp[i+1] += block offset; rp[0] = 0; re-zero cnt for the scatter pass.
__global__ __launch_bounds__(256) void scan3_kernel(
        int* __restrict__ rp, const int* __restrict__ bsum,
        int* __restrict__ cnt, int n) {
    int i = blockIdx.x * 256 + threadIdx.x;
    if (i < n) {
        rp[i + 1] += bsum[blockIdx.x];
        cnt[i] = 0;
    }
    if (i == 0) rp[0] = 0;
}

// Bucket edges by row: one packed int2 {col, val_bits} write per edge.
__global__ __launch_bounds__(256) void scatter_kernel(
        const int* __restrict__ rows, const int* __restrict__ cols,
        const float* __restrict__ vals, const int* __restrict__ rp,
        int* __restrict__ cnt, int2* __restrict__ sce, int nnz) {
    int e = blockIdx.x * 256 + threadIdx.x;
    if (e >= nnz) return;
    int r = rows[e];
    int k = atomicAdd(&cnt[r], 1);
    sce[rp[r] + k] = make_int2(cols[e], __float_as_int(vals[e]));
}

// One wave per output row, lane = dim. No atomics. acc optional (fused +=).
__global__ __launch_bounds__(256) void spmm_csr_kernel(
        const int* __restrict__ rp, const int2* __restrict__ sce,
        const float* __restrict__ xin, float* __restrict__ xnxt,
        float* __restrict__ acc, int n_nodes) {
    int wid = (int)(((long long)blockIdx.x * blockDim.x + threadIdx.x) >> 6);
    int lane = threadIdx.x & 63;
    if (wid >= n_nodes) return;
    int beg = __builtin_amdgcn_readfirstlane(rp[wid]);
    int end = __builtin_amdgcn_readfirstlane(rp[wid + 1]);
    float s = 0.f;
    int p = beg;
    for (; p + 4 <= end; p += 4) {   // 4 gathers in flight per wave
        int2 e0 = sce[p + 0], e1 = sce[p + 1], e2 = sce[p + 2], e3 = sce[p + 3];
        float g0 = xin[e0.x * EMB_C + lane];
        float g1 = xin[e1.x * EMB_C + lane];
        float g2 = xin[e2.x * EMB_C + lane];
        float g3 = xin[e3.x * EMB_C + lane];
        s = fmaf(__int_as_float(e0.y), g0, s);
        s = fmaf(__int_as_float(e1.y), g1, s);
        s = fmaf(__int_as_float(e2.y), g2, s);
        s = fmaf(__int_as_float(e3.y), g3, s);
    }
    for (; p < end; ++p) {
        int2 e = sce[p];
        s = fmaf(__int_as_float(e.y), xin[e.x * EMB_C + lane], s);
    }
    int o = wid * EMB_C + lane;
    xnxt[o] = s;
    if (acc) acc[o] += s;
}

// out = scale * (p0+p1+p2+p3)[row] at gathered rows.
__global__ __launch_bounds__(256) void gather_kernel(
        const float* __restrict__ p0, const float* __restrict__ p1,
        const float* __restrict__ p2, const float* __restrict__ p3,
        const int* __restrict__ users, const int* __restrict__ pos,
        const int* __restrict__ neg, float* __restrict__ out,
        int batch, float scale) {
    long long gid = (long long)blockIdx.x * blockDim.x + threadIdx.x;
    long long per = (long long)batch * EMB_C;
    if (gid >= 3 * per) return;
    int which = (int)(gid / per);
    long long rem = gid - (long long)which * per;
    int b = (int)(rem >> 6);
    int d = (int)(rem & 63);
    long long row;
    if (which == 0)      row = users[b];
    else if (which == 1) row = (long long)N_USER_C + pos[b];
    else                 row = (long long)N_USER_C + neg[b];
    long long idx = row * EMB_C + d;
    out[gid] = scale * (p0[idx] + p1[idx] + p2[idx] + p3[idx]);
}

// ======================= fallback (atomic) kernels ========================

__global__ __launch_bounds__(256) void fill_kernel(
        const float4* __restrict__ ue, const float4* __restrict__ ie,
        float4* __restrict__ x0, float4* __restrict__ a,
        float4* __restrict__ b, long long u4, long long t4) {
    long long i = (long long)blockIdx.x * blockDim.x + threadIdx.x;
    if (i >= t4) return;
    float4 v = (i < u4) ? ue[i] : ie[i - u4];
    x0[i] = v;
    a[i] = v;                               // acc = ego
    b[i] = make_float4(0.f, 0.f, 0.f, 0.f); // first target zeroed
}

__global__ __launch_bounds__(256) void spmm_kernel(
        const float* __restrict__ vals, const int* __restrict__ rows,
        const int* __restrict__ cols, const float* __restrict__ xin,
        float* __restrict__ xout, int nnz) {
    long long gid = (long long)blockIdx.x * blockDim.x + threadIdx.x;
    int e = (int)(gid >> 6);
    int d = (int)(gid & 63);
    if (e >= nnz) return;
    int r = rows[e];
    int c = cols[e];
    float v = vals[e];
    unsafeAtomicAdd(&xout[(long long)r * EMB_C + d], v * xin[(long long)c * EMB_C + d]);
}

__global__ __launch_bounds__(256) void acczero_kernel(
        float4* __restrict__ acc, const float4* __restrict__ src,
        float4* __restrict__ tozero, long long n4) {
    long long i = (long long)blockIdx.x * blockDim.x + threadIdx.x;
    if (i >= n4) return;
    float4 a = acc[i], s = src[i];
    a.x += s.x; a.y += s.y; a.z += s.z; a.w += s.w;
    acc[i] = a;
    if (tozero) tozero[i] = make_float4(0.f, 0.f, 0.f, 0.f);
}

// ================================ driver ==================================

extern "C" void kernel_launch(void* const* d_in, const int* in_sizes, int n_in,
                              void* d_out, int out_size, void* d_ws, size_t ws_size,
                              hipStream_t stream) {
    const float* ue    = (const float*)d_in[0];
    const float* ie    = (const float*)d_in[1];
    const float* vals  = (const float*)d_in[2];
    const int*   rows  = (const int*)d_in[3];
    const int*   cols  = (const int*)d_in[4];
    const int*   users = (const int*)d_in[5];
    const int*   pos   = (const int*)d_in[6];
    const int*   neg   = (const int*)d_in[7];
    float* out = (float*)d_out;

    const int nnz   = in_sizes[2];
    const int batch = in_sizes[5];
    const long long uelems = (long long)in_sizes[0];
    const long long total  = uelems + (long long)in_sizes[1];  // n_nodes * EMB
    const int n_nodes = (int)(total / EMB_C);
    const long long u4 = uelems / 4, t4 = total / 4;

    const int T = 256;
    const int fill_blocks = (int)((t4 + T - 1) / T);
    const int gath_blocks = (int)((3LL * batch * EMB_C + T - 1) / T);
    const int edge_blocks = (nnz + T - 1) / T;
    const int node_blocks = (n_nodes + T - 1) / T;          // scan grids
    const int spmm_blocks = (int)(((long long)n_nodes * EMB_C + T - 1) / T);

    float* w = (float*)d_ws;

    // CSR sub-buffer sizes (float units)
    const long long RN = ((n_nodes + 1 + 15) / 16) * 16;    // rp/cnt padded
    const long long csr_meta = 2 * RN + 1024;               // rp + cnt + bs
    const long long csr_edge = 2LL * nnz;                   // int2 per edge
    const size_t needA = (size_t)(4 * total + csr_meta + csr_edge) * sizeof(float);
    const size_t needB = (size_t)(3 * total + csr_meta + csr_edge) * sizeof(float);

    if (ws_size >= needB && node_blocks <= 1024) {
        const bool tierA = (ws_size >= needA);
        const long long nbuf = tierA ? 4 : 3;
        float* x0  = w;
        float* x1  = x0 + total;
        float* x2  = x1 + total;
        float* x3  = tierA ? (x2 + total) : nullptr;         // Tier A only
        float* acc = tierA ? nullptr : x2;                   // Tier B: acc buffer
        int*   rp  = (int*)(w + nbuf * total);
        int*   cnt = rp + RN;
        int*   bs  = cnt + RN;
        int2*  sce = (int2*)(bs + 1024);

        const long long z4 = (RN + 1024) / 4;   // zero cnt + bs (int4 units)

        fill_csr_kernel<<<fill_blocks, T, 0, stream>>>(
            (const float4*)ue, (const float4*)ie,
            (float4*)x0, (float4*)acc, (int4*)cnt, u4, t4, z4);

        hist_kernel<<<edge_blocks, T, 0, stream>>>(rows, cnt, nnz);
        scan1_kernel<<<node_blocks, T, 0, stream>>>(cnt, rp, bs, n_nodes);
        scan2_kernel<<<1, 1024, 0, stream>>>(bs, node_blocks);
        scan3_kernel<<<node_blocks, T, 0, stream>>>(rp, bs, cnt, n_nodes);
        scatter_kernel<<<edge_blocks, T, 0, stream>>>(rows, cols, vals, rp, cnt, sce, nnz);

        if (tierA) {
            spmm_csr_kernel<<<spmm_blocks, T, 0, stream>>>(rp, sce, x0, x1, nullptr, n_nodes);
            spmm_csr_kernel<<<spmm_blocks, T, 0, stream>>>(rp, sce, x1, x2, nullptr, n_nodes);
            spmm_csr_kernel<<<spmm_blocks, T, 0, stream>>>(rp, sce, x2, x3, nullptr, n_nodes);
            gather_kernel<<<gath_blocks, T, 0, stream>>>(
                x0, x1, x2, x3, users, pos, neg, out, batch, 0.25f);
        } else {
            spmm_csr_kernel<<<spmm_blocks, T, 0, stream>>>(rp, sce, x0, x1, acc, n_nodes);
            spmm_csr_kernel<<<spmm_blocks, T, 0, stream>>>(rp, sce, x1, x0, acc, n_nodes);
            spmm_csr_kernel<<<spmm_blocks, T, 0, stream>>>(rp, sce, x0, x1, acc, n_nodes);
            gather_kernel<<<gath_blocks, T, 0, stream>>>(
                acc, acc, acc, acc, users, pos, neg, out, batch, 0.0625f);
        }
    } else {
        // ---- Tier C: 3-buffer atomic fallback ----
        float* cur = w;
        float* nxt = cur + total;
        float* acc = nxt + total;
        fill_kernel<<<fill_blocks, T, 0, stream>>>(
            (const float4*)ue, (const float4*)ie,
            (float4*)cur, (float4*)acc, (float4*)nxt, u4, t4);
        const int espmm_blocks = (int)(((long long)nnz * EMB_C + T - 1) / T);
        for (int l = 0; l < 3; ++l) {
            spmm_kernel<<<espmm_blocks, T, 0, stream>>>(vals, rows, cols, cur, nxt, nnz);
            float4* tz = (l < 2) ? (float4*)cur : nullptr;
            acczero_kernel<<<fill_blocks, T, 0, stream>>>(
                (float4*)acc, (const float4*)nxt, tz, t4);
            float* t = cur; cur = nxt; nxt = t;
        }
        gather_kernel<<<gath_blocks, T, 0, stream>>>(
            acc, acc, acc, acc, users, pos, neg, out, batch, 0.0625f);
    }
}

// Round 6
// 668.545 us; speedup vs baseline: 3.1337x; 1.0802x over previous
//
#include <hip/hip_runtime.h>

#define EMB_C 64
#define N_USER_C 100000
#define BROWS 256        // rows per bucket
#define BSHIFT 8
#define COLBITS 18       // col fits 18 bits (n_nodes <= 262144)
#define CHUNK 8192       // edges per binscatter workgroup
#define NBMAX 640        // max buckets supported

// ============================ CSR path kernels ============================

// x0 = concat(user_emb, item_emb); optionally acc = x0; zero cnt+bs region.
__global__ __launch_bounds__(256) void fill_csr_kernel(
        const float4* __restrict__ ue, const float4* __restrict__ ie,
        float4* __restrict__ x0, float4* __restrict__ acc,
        int4* __restrict__ zint, long long u4, long long t4, long long z4) {
    long long i = (long long)blockIdx.x * blockDim.x + threadIdx.x;
    if (i < t4) {
        float4 v = (i < u4) ? ue[i] : ie[i - u4];
        x0[i] = v;
        if (acc) acc[i] = v;
    }
    if (i < z4) zint[i] = make_int4(0, 0, 0, 0);
}

__global__ __launch_bounds__(256) void hist_kernel(
        const int* __restrict__ rows, int* __restrict__ cnt, int nnz) {
    int e = blockIdx.x * 256 + threadIdx.x;
    if (e < nnz) atomicAdd(&cnt[rows[e]], 1);
}

// Block-wise inclusive scan of cnt -> rp[i+1]; block totals -> bsum.
__global__ __launch_bounds__(256) void scan1_kernel(
        const int* __restrict__ cnt, int* __restrict__ rp,
        int* __restrict__ bsum, int n) {
    __shared__ int sh[256];
    int i = blockIdx.x * 256 + threadIdx.x;
    int v = (i < n) ? cnt[i] : 0;
    sh[threadIdx.x] = v;
    __syncthreads();
    for (int off = 1; off < 256; off <<= 1) {
        int t = (threadIdx.x >= off) ? sh[threadIdx.x - off] : 0;
        __syncthreads();
        sh[threadIdx.x] += t;
        __syncthreads();
    }
    if (i < n) rp[i + 1] = sh[threadIdx.x];
    if (threadIdx.x == 255) bsum[blockIdx.x] = sh[255];
}

// Exclusive scan of bsum (nb <= 1024), single block.
__global__ __launch_bounds__(1024) void scan2_kernel(int* __restrict__ bsum, int nb) {
    __shared__ int sh[1024];
    int v = (threadIdx.x < nb) ? bsum[threadIdx.x] : 0;
    sh[threadIdx.x] = v;
    __syncthreads();
    for (int off = 1; off < 1024; off <<= 1) {
        int t = (threadIdx.x >= off) ? sh[threadIdx.x - off] : 0;
        __syncthreads();
        sh[threadIdx.x] += t;
        __syncthreads();
    }
    if (threadIdx.x < nb) bsum[threadIdx.x] = (threadIdx.x == 0) ? 0 : sh[threadIdx.x - 1];
}

// rp[i+1] += block offset; rp[0] = 0.
__global__ __launch_bounds__(256) void scan3_kernel(
        int* __restrict__ rp, const int* __restrict__ bsum, int n) {
    int i = blockIdx.x * 256 + threadIdx.x;
    if (i < n) rp[i + 1] += bsum[blockIdx.x];
    if (i == 0) rp[0] = 0;
}

// gcur[b] = rp[b*BROWS]  (bucket base = CSR offset of its first row)
__global__ __launch_bounds__(256) void initcur_kernel(
        const int* __restrict__ rp, int* __restrict__ gcur, int nb) {
    int b = blockIdx.x * 256 + threadIdx.x;
    if (b < nb) gcur[b] = rp[b << BSHIFT];
}

// Phase 1: bin edges by 256-row bucket. Packed payload {(row_low<<COLBITS)|col, val}.
// Per-WG LDS hist over a CHUNK makes writes land in ~112B contiguous runs.
__global__ __launch_bounds__(256) void binscatter_kernel(
        const int* __restrict__ rows, const int* __restrict__ cols,
        const float* __restrict__ vals, int* __restrict__ gcur,
        int2* __restrict__ bin, int nnz, int nb) {
    __shared__ int hist[NBMAX];
    __shared__ int base[NBMAX];
    __shared__ int cur[NBMAX];
    const int c0 = blockIdx.x * CHUNK;
    for (int b = threadIdx.x; b < nb; b += 256) { hist[b] = 0; cur[b] = 0; }
    __syncthreads();
    for (int i = threadIdx.x; i < CHUNK; i += 256) {
        int e = c0 + i;
        if (e < nnz) atomicAdd(&hist[rows[e] >> BSHIFT], 1);
    }
    __syncthreads();
    for (int b = threadIdx.x; b < nb; b += 256)
        if (hist[b]) base[b] = atomicAdd(&gcur[b], hist[b]);
    __syncthreads();
    for (int i = threadIdx.x; i < CHUNK; i += 256) {
        int e = c0 + i;
        if (e >= nnz) break;
        int r = rows[e];
        int b = r >> BSHIFT;
        int k = atomicAdd(&cur[b], 1);
        bin[base[b] + k] = make_int2(((r & (BROWS - 1)) << COLBITS) | cols[e],
                                     __float_as_int(vals[e]));
    }
}

// Phase 2: one WG per bucket; LDS row counters; writes stay in a ~41KB L2 window.
__global__ __launch_bounds__(256) void finscatter_kernel(
        const int2* __restrict__ bin, const int* __restrict__ rp,
        int2* __restrict__ sce, int n_nodes) {
    __shared__ int cnt[BROWS];
    const int row0 = blockIdx.x << BSHIFT;
    cnt[threadIdx.x] = 0;
    __syncthreads();
    int rend = row0 + BROWS; if (rend > n_nodes) rend = n_nodes;
    const int beg = rp[row0];
    const int end = rp[rend];
    for (int p = beg + threadIdx.x; p < end; p += 256) {
        int2 e = bin[p];
        int rl  = e.x >> COLBITS;
        int col = e.x & ((1 << COLBITS) - 1);
        int k = atomicAdd(&cnt[rl], 1);
        sce[rp[row0 + rl] + k] = make_int2(col, e.y);
    }
}

// One wave per output row, lane = dim. No atomics. acc optional (fused +=).
__global__ __launch_bounds__(256) void spmm_csr_kernel(
        const int* __restrict__ rp, const int2* __restrict__ sce,
        const float* __restrict__ xin, float* __restrict__ xnxt,
        float* __restrict__ acc, int n_nodes) {
    int wid = (int)(((long long)blockIdx.x * blockDim.x + threadIdx.x) >> 6);
    int lane = threadIdx.x & 63;
    if (wid >= n_nodes) return;
    int beg = __builtin_amdgcn_readfirstlane(rp[wid]);
    int end = __builtin_amdgcn_readfirstlane(rp[wid + 1]);
    float s = 0.f;
    int p = beg;
    for (; p + 4 <= end; p += 4) {   // 4 gathers in flight per wave
        int2 e0 = sce[p + 0], e1 = sce[p + 1], e2 = sce[p + 2], e3 = sce[p + 3];
        float g0 = xin[e0.x * EMB_C + lane];
        float g1 = xin[e1.x * EMB_C + lane];
        float g2 = xin[e2.x * EMB_C + lane];
        float g3 = xin[e3.x * EMB_C + lane];
        s = fmaf(__int_as_float(e0.y), g0, s);
        s = fmaf(__int_as_float(e1.y), g1, s);
        s = fmaf(__int_as_float(e2.y), g2, s);
        s = fmaf(__int_as_float(e3.y), g3, s);
    }
    for (; p < end; ++p) {
        int2 e = sce[p];
        s = fmaf(__int_as_float(e.y), xin[e.x * EMB_C + lane], s);
    }
    int o = wid * EMB_C + lane;
    xnxt[o] = s;
    if (acc) acc[o] += s;
}

// out = scale * (p0+p1+p2+p3)[row] at gathered rows.
__global__ __launch_bounds__(256) void gather_kernel(
        const float* __restrict__ p0, const float* __restrict__ p1,
        const float* __restrict__ p2, const float* __restrict__ p3,
        const int* __restrict__ users, const int* __restrict__ pos,
        const int* __restrict__ neg, float* __restrict__ out,
        int batch, float scale) {
    long long gid = (long long)blockIdx.x * blockDim.x + threadIdx.x;
    long long per = (long long)batch * EMB_C;
    if (gid >= 3 * per) return;
    int which = (int)(gid / per);
    long long rem = gid - (long long)which * per;
    int b = (int)(rem >> 6);
    int d = (int)(rem & 63);
    long long row;
    if (which == 0)      row = users[b];
    else if (which == 1) row = (long long)N_USER_C + pos[b];
    else                 row = (long long)N_USER_C + neg[b];
    long long idx = row * EMB_C + d;
    out[gid] = scale * (p0[idx] + p1[idx] + p2[idx] + p3[idx]);
}

// ======================= fallback (atomic) kernels ========================

__global__ __launch_bounds__(256) void fill_kernel(
        const float4* __restrict__ ue, const float4* __restrict__ ie,
        float4* __restrict__ x0, float4* __restrict__ a,
        float4* __restrict__ b, long long u4, long long t4) {
    long long i = (long long)blockIdx.x * blockDim.x + threadIdx.x;
    if (i >= t4) return;
    float4 v = (i < u4) ? ue[i] : ie[i - u4];
    x0[i] = v;
    a[i] = v;
    b[i] = make_float4(0.f, 0.f, 0.f, 0.f);
}

__global__ __launch_bounds__(256) void spmm_kernel(
        const float* __restrict__ vals, const int* __restrict__ rows,
        const int* __restrict__ cols, const float* __restrict__ xin,
        float* __restrict__ xout, int nnz) {
    long long gid = (long long)blockIdx.x * blockDim.x + threadIdx.x;
    int e = (int)(gid >> 6);
    int d = (int)(gid & 63);
    if (e >= nnz) return;
    unsafeAtomicAdd(&xout[(long long)rows[e] * EMB_C + d],
                    vals[e] * xin[(long long)cols[e] * EMB_C + d]);
}

__global__ __launch_bounds__(256) void acczero_kernel(
        float4* __restrict__ acc, const float4* __restrict__ src,
        float4* __restrict__ tozero, long long n4) {
    long long i = (long long)blockIdx.x * blockDim.x + threadIdx.x;
    if (i >= n4) return;
    float4 a = acc[i], s = src[i];
    a.x += s.x; a.y += s.y; a.z += s.z; a.w += s.w;
    acc[i] = a;
    if (tozero) tozero[i] = make_float4(0.f, 0.f, 0.f, 0.f);
}

// ================================ driver ==================================

extern "C" void kernel_launch(void* const* d_in, const int* in_sizes, int n_in,
                              void* d_out, int out_size, void* d_ws, size_t ws_size,
                              hipStream_t stream) {
    const float* ue    = (const float*)d_in[0];
    const float* ie    = (const float*)d_in[1];
    const float* vals  = (const float*)d_in[2];
    const int*   rows  = (const int*)d_in[3];
    const int*   cols  = (const int*)d_in[4];
    const int*   users = (const int*)d_in[5];
    const int*   pos   = (const int*)d_in[6];
    const int*   neg   = (const int*)d_in[7];
    float* out = (float*)d_out;

    const int nnz   = in_sizes[2];
    const int batch = in_sizes[5];
    const long long uelems = (long long)in_sizes[0];
    const long long total  = uelems + (long long)in_sizes[1];  // n_nodes * EMB
    const int n_nodes = (int)(total / EMB_C);
    const long long u4 = uelems / 4, t4 = total / 4;

    const int T = 256;
    const int fill_blocks = (int)((t4 + T - 1) / T);
    const int gath_blocks = (int)((3LL * batch * EMB_C + T - 1) / T);
    const int edge_blocks = (nnz + T - 1) / T;
    const int node_blocks = (n_nodes + T - 1) / T;
    const int spmm_blocks = (int)(((long long)n_nodes * EMB_C + T - 1) / T);
    const int nb = (n_nodes + BROWS - 1) / BROWS;           // buckets
    const int binsc_blocks = (nnz + CHUNK - 1) / CHUNK;

    float* w = (float*)d_ws;

    // layout (float units): x-buffers | rp | cnt | bs | gcur | sce ; bin aliases an x-buffer
    const long long RN = ((n_nodes + 1 + 15) / 16) * 16;
    const long long meta = 2 * RN + 2048;                   // rp + cnt + bs + gcur
    const size_t needA = (size_t)(4 * total + meta + 2LL * nnz) * sizeof(float);
    const size_t needB = (size_t)(3 * total + meta + 2LL * nnz) * sizeof(float);
    const bool fits = (node_blocks <= 1024) && (nb <= NBMAX) &&
                      (n_nodes <= (1 << COLBITS)) && (2LL * nnz <= total);

    if (fits && ws_size >= needB) {
        const bool tierA = (ws_size >= needA);
        const long long nbuf = tierA ? 4 : 3;
        float* x0  = w;
        float* x1  = x0 + total;
        float* x2  = x1 + total;
        float* x3  = tierA ? (x2 + total) : nullptr;
        float* acc = tierA ? nullptr : x2;
        int*   rp   = (int*)(w + nbuf * total);
        int*   cnt  = rp + RN;
        int*   bs   = cnt + RN;
        int*   gcur = bs + 1024;
        int2*  sce  = (int2*)(gcur + 1024);
        // bin aliases the x-buffer written only by the LAST spmm (A) / first xnxt (B)
        int2*  bin  = tierA ? (int2*)x3 : (int2*)x1;

        const long long z4 = (RN + 1024) / 4;   // zero cnt + bs (int4 units)

        fill_csr_kernel<<<fill_blocks, T, 0, stream>>>(
            (const float4*)ue, (const float4*)ie,
            (float4*)x0, (float4*)acc, (int4*)cnt, u4, t4, z4);

        hist_kernel<<<edge_blocks, T, 0, stream>>>(rows, cnt, nnz);
        scan1_kernel<<<node_blocks, T, 0, stream>>>(cnt, rp, bs, n_nodes);
        scan2_kernel<<<1, 1024, 0, stream>>>(bs, node_blocks);
        scan3_kernel<<<node_blocks, T, 0, stream>>>(rp, bs, n_nodes);
        initcur_kernel<<<(nb + T - 1) / T, T, 0, stream>>>(rp, gcur, nb);
        binscatter_kernel<<<binsc_blocks, T, 0, stream>>>(rows, cols, vals, gcur, bin, nnz, nb);
        finscatter_kernel<<<nb, T, 0, stream>>>(bin, rp, sce, n_nodes);

        if (tierA) {
            spmm_csr_kernel<<<spmm_blocks, T, 0, stream>>>(rp, sce, x0, x1, nullptr, n_nodes);
            spmm_csr_kernel<<<spmm_blocks, T, 0, stream>>>(rp, sce, x1, x2, nullptr, n_nodes);
            spmm_csr_kernel<<<spmm_blocks, T, 0, stream>>>(rp, sce, x2, x3, nullptr, n_nodes);
            gather_kernel<<<gath_blocks, T, 0, stream>>>(
                x0, x1, x2, x3, users, pos, neg, out, batch, 0.25f);
        } else {
            spmm_csr_kernel<<<spmm_blocks, T, 0, stream>>>(rp, sce, x0, x1, acc, n_nodes);
            spmm_csr_kernel<<<spmm_blocks, T, 0, stream>>>(rp, sce, x1, x0, acc, n_nodes);
            spmm_csr_kernel<<<spmm_blocks, T, 0, stream>>>(rp, sce, x0, x1, acc, n_nodes);
            gather_kernel<<<gath_blocks, T, 0, stream>>>(
                acc, acc, acc, acc, users, pos, neg, out, batch, 0.0625f);
        }
    } else {
        // ---- Tier C: 3-buffer atomic fallback ----
        float* cur = w;
        float* nxt = cur + total;
        float* acc = nxt + total;
        fill_kernel<<<fill_blocks, T, 0, stream>>>(
            (const float4*)ue, (const float4*)ie,
            (float4*)cur, (float4*)acc, (float4*)nxt, u4, t4);
        const int espmm_blocks = (int)(((long long)nnz * EMB_C + T - 1) / T);
        for (int l = 0; l < 3; ++l) {
            spmm_kernel<<<espmm_blocks, T, 0, stream>>>(vals, rows, cols, cur, nxt, nnz);
            float4* tz = (l < 2) ? (float4*)cur : nullptr;
            acczero_kernel<<<fill_blocks, T, 0, stream>>>(
                (float4*)acc, (const float4*)nxt, tz, t4);
            float* t = cur; cur = nxt; nxt = t;
        }
        gather_kernel<<<gath_blocks, T, 0, stream>>>(
            acc, acc, acc, acc, users, pos, neg, out, batch, 0.0625f);
    }
}

// Round 7
// 566.917 us; speedup vs baseline: 3.6954x; 1.1793x over previous
//
#include <hip/hip_runtime.h>

#define EMB_C 64
#define N_USER_C 100000
#define BROWS 256        // rows per bucket
#define BSHIFT 8
#define COLBITS 18       // col fits 18 bits (n_nodes <= 262144)
#define CHUNK 8192       // edges per binning workgroup
#define NBMAX 640        // max buckets supported

// ============================ CSR path kernels ============================

// x0 = concat(user_emb, item_emb); optionally acc = x0; zero bhist region.
__global__ __launch_bounds__(256) void fill_csr_kernel(
        const float4* __restrict__ ue, const float4* __restrict__ ie,
        float4* __restrict__ x0, float4* __restrict__ acc,
        int4* __restrict__ zint, long long u4, long long t4, long long z4) {
    long long i = (long long)blockIdx.x * blockDim.x + threadIdx.x;
    if (i < t4) {
        float4 v = (i < u4) ? ue[i] : ie[i - u4];
        x0[i] = v;
        if (acc) acc[i] = v;
    }
    if (i < z4) zint[i] = make_int4(0, 0, 0, 0);
}

// Bucket-level histogram via per-WG LDS hist; <=nb global atomics per WG.
__global__ __launch_bounds__(256) void buckethist_kernel(
        const int* __restrict__ rows, int* __restrict__ bhist, int nnz, int nb) {
    __shared__ int hist[NBMAX];
    for (int b = threadIdx.x; b < nb; b += 256) hist[b] = 0;
    __syncthreads();
    const int c0 = blockIdx.x * CHUNK;
    for (int i = threadIdx.x; i < CHUNK; i += 256) {
        int e = c0 + i;
        if (e < nnz) atomicAdd(&hist[rows[e] >> BSHIFT], 1);
    }
    __syncthreads();
    for (int b = threadIdx.x; b < nb; b += 256)
        if (hist[b]) atomicAdd(&bhist[b], hist[b]);
}

// Single block: exclusive-scan bucket hist -> bbase & gcur; rp[n_nodes]=nnz.
__global__ __launch_bounds__(1024) void bucketscan_kernel(
        const int* __restrict__ bhist, int* __restrict__ bbase,
        int* __restrict__ gcur, int* __restrict__ rp,
        int nb, int nnz, int n_nodes) {
    __shared__ int sh[1024];
    int v = (threadIdx.x < nb) ? bhist[threadIdx.x] : 0;
    sh[threadIdx.x] = v;
    __syncthreads();
    for (int off = 1; off < 1024; off <<= 1) {
        int t = (threadIdx.x >= off) ? sh[threadIdx.x - off] : 0;
        __syncthreads();
        sh[threadIdx.x] += t;
        __syncthreads();
    }
    if (threadIdx.x < nb) {
        int excl = sh[threadIdx.x] - v;
        bbase[threadIdx.x] = excl;
        gcur[threadIdx.x]  = excl;
    }
    if (threadIdx.x == 0) { bbase[nb] = nnz; rp[n_nodes] = nnz; }
}

// Phase 1: bin edges by bucket. Payload {(row_low<<COLBITS)|col, val_bits}.
__global__ __launch_bounds__(256) void binscatter_kernel(
        const int* __restrict__ rows, const int* __restrict__ cols,
        const float* __restrict__ vals, int* __restrict__ gcur,
        int2* __restrict__ bin, int nnz, int nb) {
    __shared__ int hist[NBMAX];
    __shared__ int base[NBMAX];
    __shared__ int cur[NBMAX];
    const int c0 = blockIdx.x * CHUNK;
    for (int b = threadIdx.x; b < nb; b += 256) { hist[b] = 0; cur[b] = 0; }
    __syncthreads();
    for (int i = threadIdx.x; i < CHUNK; i += 256) {
        int e = c0 + i;
        if (e < nnz) atomicAdd(&hist[rows[e] >> BSHIFT], 1);
    }
    __syncthreads();
    for (int b = threadIdx.x; b < nb; b += 256)
        if (hist[b]) base[b] = atomicAdd(&gcur[b], hist[b]);
    __syncthreads();
    for (int i = threadIdx.x; i < CHUNK; i += 256) {
        int e = c0 + i;
        if (e >= nnz) break;
        int r = rows[e];
        int b = r >> BSHIFT;
        int k = atomicAdd(&cur[b], 1);
        bin[base[b] + k] = make_int2(((r & (BROWS - 1)) << COLBITS) | cols[e],
                                     __float_as_int(vals[e]));
    }
}

// Phase 2 (one WG per bucket): count rows in LDS, scan, WRITE rp for this
// bucket, then scatter edges into row order. No global per-row histogram.
__global__ __launch_bounds__(256) void finscatter_kernel(
        const int2* __restrict__ bin, const int* __restrict__ bbase,
        int* __restrict__ rp, int2* __restrict__ sce, int n_nodes) {
    __shared__ int cnt[BROWS];
    __shared__ int sh[BROWS];
    __shared__ int cur[BROWS];
    const int row0 = blockIdx.x << BSHIFT;
    const int tid = threadIdx.x;
    cnt[tid] = 0;
    __syncthreads();
    const int bb = bbase[blockIdx.x];
    const int be = bbase[blockIdx.x + 1];
    for (int p = bb + tid; p < be; p += 256)
        atomicAdd(&cnt[bin[p].x >> COLBITS], 1);
    __syncthreads();
    int v = cnt[tid];
    sh[tid] = v;
    __syncthreads();
    for (int off = 1; off < 256; off <<= 1) {
        int t = (tid >= off) ? sh[tid - off] : 0;
        __syncthreads();
        sh[tid] += t;
        __syncthreads();
    }
    int excl = sh[tid] - v;
    cur[tid] = excl;
    if (row0 + tid < n_nodes) rp[row0 + tid] = bb + excl;   // coalesced rp build
    __syncthreads();
    for (int p = bb + tid; p < be; p += 256) {
        int2 e = bin[p];
        int rl = e.x >> COLBITS;
        int k = atomicAdd(&cur[rl], 1);
        sce[bb + k] = make_int2(e.x & ((1 << COLBITS) - 1), e.y);
    }
}

// One wave per output row, lane = dim. No atomics. acc optional (fused +=).
__global__ __launch_bounds__(256) void spmm_csr_kernel(
        const int* __restrict__ rp, const int2* __restrict__ sce,
        const float* __restrict__ xin, float* __restrict__ xnxt,
        float* __restrict__ acc, int n_nodes) {
    int wid = (int)(((long long)blockIdx.x * blockDim.x + threadIdx.x) >> 6);
    int lane = threadIdx.x & 63;
    if (wid >= n_nodes) return;
    int beg = __builtin_amdgcn_readfirstlane(rp[wid]);
    int end = __builtin_amdgcn_readfirstlane(rp[wid + 1]);
    float s = 0.f;
    int p = beg;
    for (; p + 4 <= end; p += 4) {   // 4 gathers in flight per wave
        int2 e0 = sce[p + 0], e1 = sce[p + 1], e2 = sce[p + 2], e3 = sce[p + 3];
        float g0 = xin[e0.x * EMB_C + lane];
        float g1 = xin[e1.x * EMB_C + lane];
        float g2 = xin[e2.x * EMB_C + lane];
        float g3 = xin[e3.x * EMB_C + lane];
        s = fmaf(__int_as_float(e0.y), g0, s);
        s = fmaf(__int_as_float(e1.y), g1, s);
        s = fmaf(__int_as_float(e2.y), g2, s);
        s = fmaf(__int_as_float(e3.y), g3, s);
    }
    for (; p < end; ++p) {
        int2 e = sce[p];
        s = fmaf(__int_as_float(e.y), xin[e.x * EMB_C + lane], s);
    }
    int o = wid * EMB_C + lane;
    xnxt[o] = s;
    if (acc) acc[o] += s;
}

// out = scale * (p0+p1+p2+p3)[row] at gathered rows.
__global__ __launch_bounds__(256) void gather_kernel(
        const float* __restrict__ p0, const float* __restrict__ p1,
        const float* __restrict__ p2, const float* __restrict__ p3,
        const int* __restrict__ users, const int* __restrict__ pos,
        const int* __restrict__ neg, float* __restrict__ out,
        int batch, float scale) {
    long long gid = (long long)blockIdx.x * blockDim.x + threadIdx.x;
    long long per = (long long)batch * EMB_C;
    if (gid >= 3 * per) return;
    int which = (int)(gid / per);
    long long rem = gid - (long long)which * per;
    int b = (int)(rem >> 6);
    int d = (int)(rem & 63);
    long long row;
    if (which == 0)      row = users[b];
    else if (which == 1) row = (long long)N_USER_C + pos[b];
    else                 row = (long long)N_USER_C + neg[b];
    long long idx = row * EMB_C + d;
    out[gid] = scale * (p0[idx] + p1[idx] + p2[idx] + p3[idx]);
}

// ======================= fallback (atomic) kernels ========================

__global__ __launch_bounds__(256) void fill_kernel(
        const float4* __restrict__ ue, const float4* __restrict__ ie,
        float4* __restrict__ x0, float4* __restrict__ a,
        float4* __restrict__ b, long long u4, long long t4) {
    long long i = (long long)blockIdx.x * blockDim.x + threadIdx.x;
    if (i >= t4) return;
    float4 v = (i < u4) ? ue[i] : ie[i - u4];
    x0[i] = v;
    a[i] = v;
    b[i] = make_float4(0.f, 0.f, 0.f, 0.f);
}

__global__ __launch_bounds__(256) void spmm_kernel(
        const float* __restrict__ vals, const int* __restrict__ rows,
        const int* __restrict__ cols, const float* __restrict__ xin,
        float* __restrict__ xout, int nnz) {
    long long gid = (long long)blockIdx.x * blockDim.x + threadIdx.x;
    int e = (int)(gid >> 6);
    int d = (int)(gid & 63);
    if (e >= nnz) return;
    unsafeAtomicAdd(&xout[(long long)rows[e] * EMB_C + d],
                    vals[e] * xin[(long long)cols[e] * EMB_C + d]);
}

__global__ __launch_bounds__(256) void acczero_kernel(
        float4* __restrict__ acc, const float4* __restrict__ src,
        float4* __restrict__ tozero, long long n4) {
    long long i = (long long)blockIdx.x * blockDim.x + threadIdx.x;
    if (i >= n4) return;
    float4 a = acc[i], s = src[i];
    a.x += s.x; a.y += s.y; a.z += s.z; a.w += s.w;
    acc[i] = a;
    if (tozero) tozero[i] = make_float4(0.f, 0.f, 0.f, 0.f);
}

// ================================ driver ==================================

extern "C" void kernel_launch(void* const* d_in, const int* in_sizes, int n_in,
                              void* d_out, int out_size, void* d_ws, size_t ws_size,
                              hipStream_t stream) {
    const float* ue    = (const float*)d_in[0];
    const float* ie    = (const float*)d_in[1];
    const float* vals  = (const float*)d_in[2];
    const int*   rows  = (const int*)d_in[3];
    const int*   cols  = (const int*)d_in[4];
    const int*   users = (const int*)d_in[5];
    const int*   pos   = (const int*)d_in[6];
    const int*   neg   = (const int*)d_in[7];
    float* out = (float*)d_out;

    const int nnz   = in_sizes[2];
    const int batch = in_sizes[5];
    const long long uelems = (long long)in_sizes[0];
    const long long total  = uelems + (long long)in_sizes[1];  // n_nodes * EMB
    const int n_nodes = (int)(total / EMB_C);
    const long long u4 = uelems / 4, t4 = total / 4;

    const int T = 256;
    const int fill_blocks = (int)((t4 + T - 1) / T);
    const int gath_blocks = (int)((3LL * batch * EMB_C + T - 1) / T);
    const int spmm_blocks = (int)(((long long)n_nodes * EMB_C + T - 1) / T);
    const int nb = (n_nodes + BROWS - 1) / BROWS;           // buckets
    const int chunk_blocks = (nnz + CHUNK - 1) / CHUNK;

    float* w = (float*)d_ws;

    // layout (floats): x-bufs | rp(RN) | bhist(1024) | bbase(1024) | gcur(1024) | sce(2*nnz)
    // bin aliases an x-buffer.
    const long long RN = ((n_nodes + 1 + 15) / 16) * 16;
    const long long meta = RN + 3072;
    const size_t needA = (size_t)(4 * total + meta + 2LL * nnz) * sizeof(float);
    const size_t needB = (size_t)(3 * total + meta + 2LL * nnz) * sizeof(float);
    const bool fits = (nb <= NBMAX) && (n_nodes <= (1 << COLBITS)) &&
                      (2LL * nnz <= total);

    if (fits && ws_size >= needB) {
        const bool tierA = (ws_size >= needA);
        const long long nbuf = tierA ? 4 : 3;
        float* x0  = w;
        float* x1  = x0 + total;
        float* x2  = x1 + total;
        float* x3  = tierA ? (x2 + total) : nullptr;
        float* acc = tierA ? nullptr : x2;
        int*   rp    = (int*)(w + nbuf * total);
        int*   bhist = rp + RN;
        int*   bbase = bhist + 1024;
        int*   gcur  = bbase + 1024;
        int2*  sce   = (int2*)(gcur + 1024);
        // bin aliases the x-buffer written only later by SpMM
        int2*  bin   = tierA ? (int2*)x3 : (int2*)x1;

        fill_csr_kernel<<<fill_blocks, T, 0, stream>>>(
            (const float4*)ue, (const float4*)ie,
            (float4*)x0, (float4*)acc, (int4*)bhist, u4, t4, 1024 / 4);

        buckethist_kernel<<<chunk_blocks, T, 0, stream>>>(rows, bhist, nnz, nb);
        bucketscan_kernel<<<1, 1024, 0, stream>>>(bhist, bbase, gcur, rp, nb, nnz, n_nodes);
        binscatter_kernel<<<chunk_blocks, T, 0, stream>>>(rows, cols, vals, gcur, bin, nnz, nb);
        finscatter_kernel<<<nb, T, 0, stream>>>(bin, bbase, rp, sce, n_nodes);

        if (tierA) {
            spmm_csr_kernel<<<spmm_blocks, T, 0, stream>>>(rp, sce, x0, x1, nullptr, n_nodes);
            spmm_csr_kernel<<<spmm_blocks, T, 0, stream>>>(rp, sce, x1, x2, nullptr, n_nodes);
            spmm_csr_kernel<<<spmm_blocks, T, 0, stream>>>(rp, sce, x2, x3, nullptr, n_nodes);
            gather_kernel<<<gath_blocks, T, 0, stream>>>(
                x0, x1, x2, x3, users, pos, neg, out, batch, 0.25f);
        } else {
            spmm_csr_kernel<<<spmm_blocks, T, 0, stream>>>(rp, sce, x0, x1, acc, n_nodes);
            spmm_csr_kernel<<<spmm_blocks, T, 0, stream>>>(rp, sce, x1, x0, acc, n_nodes);
            spmm_csr_kernel<<<spmm_blocks, T, 0, stream>>>(rp, sce, x0, x1, acc, n_nodes);
            gather_kernel<<<gath_blocks, T, 0, stream>>>(
                acc, acc, acc, acc, users, pos, neg, out, batch, 0.0625f);
        }
    } else {
        // ---- Tier C: 3-buffer atomic fallback ----
        float* cur = w;
        float* nxt = cur + total;
        float* acc = nxt + total;
        fill_kernel<<<fill_blocks, T, 0, stream>>>(
            (const float4*)ue, (const float4*)ie,
            (float4*)cur, (float4*)acc, (float4*)nxt, u4, t4);
        const int espmm_blocks = (int)(((long long)nnz * EMB_C + T - 1) / T);
        for (int l = 0; l < 3; ++l) {
            spmm_kernel<<<espmm_blocks, T, 0, stream>>>(vals, rows, cols, cur, nxt, nnz);
            float4* tz = (l < 2) ? (float4*)cur : nullptr;
            acczero_kernel<<<fill_blocks, T, 0, stream>>>(
                (float4*)acc, (const float4*)nxt, tz, t4);
            float* t = cur; cur = nxt; nxt = t;
        }
        gather_kernel<<<gath_blocks, T, 0, stream>>>(
            acc, acc, acc, acc, users, pos, neg, out, batch, 0.0625f);
    }
}

// Round 8
// 556.738 us; speedup vs baseline: 3.7630x; 1.0183x over previous
//
#include <hip/hip_runtime.h>

#define EMB_C 64
#define N_USER_C 100000
#define BROWS 256        // rows per bucket
#define BSHIFT 8
#define COLBITS 18       // col fits 18 bits (n_nodes <= 262144)
#define CHUNK 8192       // edges per binning workgroup
#define NBMAX 640        // max buckets supported

// ============================ CSR path kernels ============================

// x0 = concat(user_emb, item_emb); optionally acc = x0; zero bhist region.
__global__ __launch_bounds__(256) void fill_csr_kernel(
        const float4* __restrict__ ue, const float4* __restrict__ ie,
        float4* __restrict__ x0, float4* __restrict__ acc,
        int4* __restrict__ zint, long long u4, long long t4, long long z4) {
    long long i = (long long)blockIdx.x * blockDim.x + threadIdx.x;
    if (i < t4) {
        float4 v = (i < u4) ? ue[i] : ie[i - u4];
        x0[i] = v;
        if (acc) acc[i] = v;
    }
    if (i < z4) zint[i] = make_int4(0, 0, 0, 0);
}

// Bucket-level histogram via per-WG LDS hist; <=nb global atomics per WG.
__global__ __launch_bounds__(256) void buckethist_kernel(
        const int* __restrict__ rows, int* __restrict__ bhist, int nnz, int nb) {
    __shared__ int hist[NBMAX];
    for (int b = threadIdx.x; b < nb; b += 256) hist[b] = 0;
    __syncthreads();
    const int c0 = blockIdx.x * CHUNK;
    for (int i = threadIdx.x; i < CHUNK; i += 256) {
        int e = c0 + i;
        if (e < nnz) atomicAdd(&hist[rows[e] >> BSHIFT], 1);
    }
    __syncthreads();
    for (int b = threadIdx.x; b < nb; b += 256)
        if (hist[b]) atomicAdd(&bhist[b], hist[b]);
}

// Single block: exclusive-scan bucket hist -> bbase & gcur; rp[n_nodes]=nnz.
__global__ __launch_bounds__(1024) void bucketscan_kernel(
        const int* __restrict__ bhist, int* __restrict__ bbase,
        int* __restrict__ gcur, int* __restrict__ rp,
        int nb, int nnz, int n_nodes) {
    __shared__ int sh[1024];
    int v = (threadIdx.x < nb) ? bhist[threadIdx.x] : 0;
    sh[threadIdx.x] = v;
    __syncthreads();
    for (int off = 1; off < 1024; off <<= 1) {
        int t = (threadIdx.x >= off) ? sh[threadIdx.x - off] : 0;
        __syncthreads();
        sh[threadIdx.x] += t;
        __syncthreads();
    }
    if (threadIdx.x < nb) {
        int excl = sh[threadIdx.x] - v;
        bbase[threadIdx.x] = excl;
        gcur[threadIdx.x]  = excl;
    }
    if (threadIdx.x == 0) { bbase[nb] = nnz; rp[n_nodes] = nnz; }
}

// Phase 1: bin edges by bucket. Payload {(row_low<<COLBITS)|col, val_bits}.
__global__ __launch_bounds__(256) void binscatter_kernel(
        const int* __restrict__ rows, const int* __restrict__ cols,
        const float* __restrict__ vals, int* __restrict__ gcur,
        int2* __restrict__ bin, int nnz, int nb) {
    __shared__ int hist[NBMAX];
    __shared__ int base[NBMAX];
    __shared__ int cur[NBMAX];
    const int c0 = blockIdx.x * CHUNK;
    for (int b = threadIdx.x; b < nb; b += 256) { hist[b] = 0; cur[b] = 0; }
    __syncthreads();
    for (int i = threadIdx.x; i < CHUNK; i += 256) {
        int e = c0 + i;
        if (e < nnz) atomicAdd(&hist[rows[e] >> BSHIFT], 1);
    }
    __syncthreads();
    for (int b = threadIdx.x; b < nb; b += 256)
        if (hist[b]) base[b] = atomicAdd(&gcur[b], hist[b]);
    __syncthreads();
    for (int i = threadIdx.x; i < CHUNK; i += 256) {
        int e = c0 + i;
        if (e >= nnz) break;
        int r = rows[e];
        int b = r >> BSHIFT;
        int k = atomicAdd(&cur[b], 1);
        bin[base[b] + k] = make_int2(((r & (BROWS - 1)) << COLBITS) | cols[e],
                                     __float_as_int(vals[e]));
    }
}

// Phase 2 (one WG per bucket): count rows in LDS, scan, WRITE rp for this
// bucket, then scatter edges into row order. No global per-row histogram.
__global__ __launch_bounds__(256) void finscatter_kernel(
        const int2* __restrict__ bin, const int* __restrict__ bbase,
        int* __restrict__ rp, int2* __restrict__ sce, int n_nodes) {
    __shared__ int cnt[BROWS];
    __shared__ int sh[BROWS];
    __shared__ int cur[BROWS];
    const int row0 = blockIdx.x << BSHIFT;
    const int tid = threadIdx.x;
    cnt[tid] = 0;
    __syncthreads();
    const int bb = bbase[blockIdx.x];
    const int be = bbase[blockIdx.x + 1];
    for (int p = bb + tid; p < be; p += 256)
        atomicAdd(&cnt[bin[p].x >> COLBITS], 1);
    __syncthreads();
    int v = cnt[tid];
    sh[tid] = v;
    __syncthreads();
    for (int off = 1; off < 256; off <<= 1) {
        int t = (tid >= off) ? sh[tid - off] : 0;
        __syncthreads();
        sh[tid] += t;
        __syncthreads();
    }
    int excl = sh[tid] - v;
    cur[tid] = excl;
    if (row0 + tid < n_nodes) rp[row0 + tid] = bb + excl;   // coalesced rp build
    __syncthreads();
    for (int p = bb + tid; p < be; p += 256) {
        int2 e = bin[p];
        int rl = e.x >> COLBITS;
        int k = atomicAdd(&cur[rl], 1);
        sce[bb + k] = make_int2(e.x & ((1 << COLBITS) - 1), e.y);
    }
}

// One wave per output row, lane = dim. Explicit 8-deep MLP: batch 8 payload
// loads, 8 independent gathers, 8 FMAs into 4 rotating accumulators.
__global__ __launch_bounds__(256) void spmm_csr_kernel(
        const int* __restrict__ rp, const int2* __restrict__ sce,
        const float* __restrict__ xin, float* __restrict__ xnxt,
        float* __restrict__ acc, int n_nodes) {
    int wid = (int)(((long long)blockIdx.x * blockDim.x + threadIdx.x) >> 6);
    int lane = threadIdx.x & 63;
    if (wid >= n_nodes) return;
    int beg = __builtin_amdgcn_readfirstlane(rp[wid]);
    int end = __builtin_amdgcn_readfirstlane(rp[wid + 1]);
    const unsigned long long* __restrict__ sceq = (const unsigned long long*)sce;
    float s0 = 0.f, s1 = 0.f, s2 = 0.f, s3 = 0.f;
    int p = beg;
    for (; p + 8 <= end; p += 8) {
        unsigned long long u0 = __builtin_nontemporal_load(sceq + p + 0);
        unsigned long long u1 = __builtin_nontemporal_load(sceq + p + 1);
        unsigned long long u2 = __builtin_nontemporal_load(sceq + p + 2);
        unsigned long long u3 = __builtin_nontemporal_load(sceq + p + 3);
        unsigned long long u4 = __builtin_nontemporal_load(sceq + p + 4);
        unsigned long long u5 = __builtin_nontemporal_load(sceq + p + 5);
        unsigned long long u6 = __builtin_nontemporal_load(sceq + p + 6);
        unsigned long long u7 = __builtin_nontemporal_load(sceq + p + 7);
        float g0 = xin[((int)(unsigned)u0) * EMB_C + lane];
        float g1 = xin[((int)(unsigned)u1) * EMB_C + lane];
        float g2 = xin[((int)(unsigned)u2) * EMB_C + lane];
        float g3 = xin[((int)(unsigned)u3) * EMB_C + lane];
        float g4 = xin[((int)(unsigned)u4) * EMB_C + lane];
        float g5 = xin[((int)(unsigned)u5) * EMB_C + lane];
        float g6 = xin[((int)(unsigned)u6) * EMB_C + lane];
        float g7 = xin[((int)(unsigned)u7) * EMB_C + lane];
        s0 = fmaf(__int_as_float((int)(u0 >> 32)), g0, s0);
        s1 = fmaf(__int_as_float((int)(u1 >> 32)), g1, s1);
        s2 = fmaf(__int_as_float((int)(u2 >> 32)), g2, s2);
        s3 = fmaf(__int_as_float((int)(u3 >> 32)), g3, s3);
        s0 = fmaf(__int_as_float((int)(u4 >> 32)), g4, s0);
        s1 = fmaf(__int_as_float((int)(u5 >> 32)), g5, s1);
        s2 = fmaf(__int_as_float((int)(u6 >> 32)), g6, s2);
        s3 = fmaf(__int_as_float((int)(u7 >> 32)), g7, s3);
    }
    for (; p + 4 <= end; p += 4) {
        unsigned long long u0 = __builtin_nontemporal_load(sceq + p + 0);
        unsigned long long u1 = __builtin_nontemporal_load(sceq + p + 1);
        unsigned long long u2 = __builtin_nontemporal_load(sceq + p + 2);
        unsigned long long u3 = __builtin_nontemporal_load(sceq + p + 3);
        float g0 = xin[((int)(unsigned)u0) * EMB_C + lane];
        float g1 = xin[((int)(unsigned)u1) * EMB_C + lane];
        float g2 = xin[((int)(unsigned)u2) * EMB_C + lane];
        float g3 = xin[((int)(unsigned)u3) * EMB_C + lane];
        s0 = fmaf(__int_as_float((int)(u0 >> 32)), g0, s0);
        s1 = fmaf(__int_as_float((int)(u1 >> 32)), g1, s1);
        s2 = fmaf(__int_as_float((int)(u2 >> 32)), g2, s2);
        s3 = fmaf(__int_as_float((int)(u3 >> 32)), g3, s3);
    }
    for (; p < end; ++p) {
        unsigned long long u = __builtin_nontemporal_load(sceq + p);
        s0 = fmaf(__int_as_float((int)(u >> 32)),
                  xin[((int)(unsigned)u) * EMB_C + lane], s0);
    }
    float s = (s0 + s1) + (s2 + s3);
    int o = wid * EMB_C + lane;
    __builtin_nontemporal_store(s, &xnxt[o]);
    if (acc) acc[o] += s;
}

// out = scale * (p0+p1+p2+p3)[row] at gathered rows.
__global__ __launch_bounds__(256) void gather_kernel(
        const float* __restrict__ p0, const float* __restrict__ p1,
        const float* __restrict__ p2, const float* __restrict__ p3,
        const int* __restrict__ users, const int* __restrict__ pos,
        const int* __restrict__ neg, float* __restrict__ out,
        int batch, float scale) {
    long long gid = (long long)blockIdx.x * blockDim.x + threadIdx.x;
    long long per = (long long)batch * EMB_C;
    if (gid >= 3 * per) return;
    int which = (int)(gid / per);
    long long rem = gid - (long long)which * per;
    int b = (int)(rem >> 6);
    int d = (int)(rem & 63);
    long long row;
    if (which == 0)      row = users[b];
    else if (which == 1) row = (long long)N_USER_C + pos[b];
    else                 row = (long long)N_USER_C + neg[b];
    long long idx = row * EMB_C + d;
    out[gid] = scale * (p0[idx] + p1[idx] + p2[idx] + p3[idx]);
}

// ======================= fallback (atomic) kernels ========================

__global__ __launch_bounds__(256) void fill_kernel(
        const float4* __restrict__ ue, const float4* __restrict__ ie,
        float4* __restrict__ x0, float4* __restrict__ a,
        float4* __restrict__ b, long long u4, long long t4) {
    long long i = (long long)blockIdx.x * blockDim.x + threadIdx.x;
    if (i >= t4) return;
    float4 v = (i < u4) ? ue[i] : ie[i - u4];
    x0[i] = v;
    a[i] = v;
    b[i] = make_float4(0.f, 0.f, 0.f, 0.f);
}

__global__ __launch_bounds__(256) void spmm_kernel(
        const float* __restrict__ vals, const int* __restrict__ rows,
        const int* __restrict__ cols, const float* __restrict__ xin,
        float* __restrict__ xout, int nnz) {
    long long gid = (long long)blockIdx.x * blockDim.x + threadIdx.x;
    int e = (int)(gid >> 6);
    int d = (int)(gid & 63);
    if (e >= nnz) return;
    unsafeAtomicAdd(&xout[(long long)rows[e] * EMB_C + d],
                    vals[e] * xin[(long long)cols[e] * EMB_C + d]);
}

__global__ __launch_bounds__(256) void acczero_kernel(
        float4* __restrict__ acc, const float4* __restrict__ src,
        float4* __restrict__ tozero, long long n4) {
    long long i = (long long)blockIdx.x * blockDim.x + threadIdx.x;
    if (i >= n4) return;
    float4 a = acc[i], s = src[i];
    a.x += s.x; a.y += s.y; a.z += s.z; a.w += s.w;
    acc[i] = a;
    if (tozero) tozero[i] = make_float4(0.f, 0.f, 0.f, 0.f);
}

// ================================ driver ==================================

extern "C" void kernel_launch(void* const* d_in, const int* in_sizes, int n_in,
                              void* d_out, int out_size, void* d_ws, size_t ws_size,
                              hipStream_t stream) {
    const float* ue    = (const float*)d_in[0];
    const float* ie    = (const float*)d_in[1];
    const float* vals  = (const float*)d_in[2];
    const int*   rows  = (const int*)d_in[3];
    const int*   cols  = (const int*)d_in[4];
    const int*   users = (const int*)d_in[5];
    const int*   pos   = (const int*)d_in[6];
    const int*   neg   = (const int*)d_in[7];
    float* out = (float*)d_out;

    const int nnz   = in_sizes[2];
    const int batch = in_sizes[5];
    const long long uelems = (long long)in_sizes[0];
    const long long total  = uelems + (long long)in_sizes[1];  // n_nodes * EMB
    const int n_nodes = (int)(total / EMB_C);
    const long long u4 = uelems / 4, t4 = total / 4;

    const int T = 256;
    const int fill_blocks = (int)((t4 + T - 1) / T);
    const int gath_blocks = (int)((3LL * batch * EMB_C + T - 1) / T);
    const int spmm_blocks = (int)(((long long)n_nodes * EMB_C + T - 1) / T);
    const int nb = (n_nodes + BROWS - 1) / BROWS;           // buckets
    const int chunk_blocks = (nnz + CHUNK - 1) / CHUNK;

    float* w = (float*)d_ws;

    // layout (floats): x-bufs | rp(RN) | bhist(1024) | bbase(1024) | gcur(1024) | sce(2*nnz)
    // bin aliases an x-buffer.
    const long long RN = ((n_nodes + 1 + 15) / 16) * 16;
    const long long meta = RN + 3072;
    const size_t needA = (size_t)(4 * total + meta + 2LL * nnz) * sizeof(float);
    const size_t needB = (size_t)(3 * total + meta + 2LL * nnz) * sizeof(float);
    const bool fits = (nb <= NBMAX) && (n_nodes <= (1 << COLBITS)) &&
                      (2LL * nnz <= total);

    if (fits && ws_size >= needB) {
        const bool tierA = (ws_size >= needA);
        const long long nbuf = tierA ? 4 : 3;
        float* x0  = w;
        float* x1  = x0 + total;
        float* x2  = x1 + total;
        float* x3  = tierA ? (x2 + total) : nullptr;
        float* acc = tierA ? nullptr : x2;
        int*   rp    = (int*)(w + nbuf * total);
        int*   bhist = rp + RN;
        int*   bbase = bhist + 1024;
        int*   gcur  = bbase + 1024;
        int2*  sce   = (int2*)(gcur + 1024);
        // bin aliases the x-buffer written only later by SpMM
        int2*  bin   = tierA ? (int2*)x3 : (int2*)x1;

        fill_csr_kernel<<<fill_blocks, T, 0, stream>>>(
            (const float4*)ue, (const float4*)ie,
            (float4*)x0, (float4*)acc, (int4*)bhist, u4, t4, 1024 / 4);

        buckethist_kernel<<<chunk_blocks, T, 0, stream>>>(rows, bhist, nnz, nb);
        bucketscan_kernel<<<1, 1024, 0, stream>>>(bhist, bbase, gcur, rp, nb, nnz, n_nodes);
        binscatter_kernel<<<chunk_blocks, T, 0, stream>>>(rows, cols, vals, gcur, bin, nnz, nb);
        finscatter_kernel<<<nb, T, 0, stream>>>(bin, bbase, rp, sce, n_nodes);

        if (tierA) {
            spmm_csr_kernel<<<spmm_blocks, T, 0, stream>>>(rp, sce, x0, x1, nullptr, n_nodes);
            spmm_csr_kernel<<<spmm_blocks, T, 0, stream>>>(rp, sce, x1, x2, nullptr, n_nodes);
            spmm_csr_kernel<<<spmm_blocks, T, 0, stream>>>(rp, sce, x2, x3, nullptr, n_nodes);
            gather_kernel<<<gath_blocks, T, 0, stream>>>(
                x0, x1, x2, x3, users, pos, neg, out, batch, 0.25f);
        } else {
            spmm_csr_kernel<<<spmm_blocks, T, 0, stream>>>(rp, sce, x0, x1, acc, n_nodes);
            spmm_csr_kernel<<<spmm_blocks, T, 0, stream>>>(rp, sce, x1, x0, acc, n_nodes);
            spmm_csr_kernel<<<spmm_blocks, T, 0, stream>>>(rp, sce, x0, x1, acc, n_nodes);
            gather_kernel<<<gath_blocks, T, 0, stream>>>(
                acc, acc, acc, acc, users, pos, neg, out, batch, 0.0625f);
        }
    } else {
        // ---- Tier C: 3-buffer atomic fallback ----
        float* cur = w;
        float* nxt = cur + total;
        float* acc = nxt + total;
        fill_kernel<<<fill_blocks, T, 0, stream>>>(
            (const float4*)ue, (const float4*)ie,
            (float4*)cur, (float4*)acc, (float4*)nxt, u4, t4);
        const int espmm_blocks = (int)(((long long)nnz * EMB_C + T - 1) / T);
        for (int l = 0; l < 3; ++l) {
            spmm_kernel<<<espmm_blocks, T, 0, stream>>>(vals, rows, cols, cur, nxt, nnz);
            float4* tz = (l < 2) ? (float4*)cur : nullptr;
            acczero_kernel<<<fill_blocks, T, 0, stream>>>(
                (float4*)acc, (const float4*)nxt, tz, t4);
            float* t = cur; cur = nxt; nxt = t;
        }
        gather_kernel<<<gath_blocks, T, 0, stream>>>(
            acc, acc, acc, acc, users, pos, neg, out, batch, 0.0625f);
    }
}

// Round 9
// 448.191 us; speedup vs baseline: 4.6743x; 1.2422x over previous
//
#include <hip/hip_runtime.h>
#include <hip/hip_fp16.h>

#define EMB_C 64
#define N_USER_C 100000
#define BROWS 256        // rows per bucket
#define BSHIFT 8
#define COLBITS 18       // col fits 18 bits (n_nodes <= 262144)
#define CHUNK 8192       // edges per binning workgroup
#define NBMAX 640        // max buckets supported

// ============================ CSR path kernels ============================

// x0h = fp16(concat(user_emb, item_emb)); zero bhist region.
__global__ __launch_bounds__(256) void fill_h_kernel(
        const float4* __restrict__ ue, const float4* __restrict__ ie,
        ushort4* __restrict__ x0, int4* __restrict__ zint,
        long long u4, long long t4, long long z4) {
    long long i = (long long)blockIdx.x * blockDim.x + threadIdx.x;
    if (i < t4) {
        float4 v = (i < u4) ? ue[i] : ie[i - u4];
        ushort4 h;
        h.x = __half_as_ushort(__float2half(v.x));
        h.y = __half_as_ushort(__float2half(v.y));
        h.z = __half_as_ushort(__float2half(v.z));
        h.w = __half_as_ushort(__float2half(v.w));
        x0[i] = h;
    }
    if (i < z4) zint[i] = make_int4(0, 0, 0, 0);
}

// Bucket-level histogram via per-WG LDS hist; <=nb global atomics per WG.
__global__ __launch_bounds__(256) void buckethist_kernel(
        const int* __restrict__ rows, int* __restrict__ bhist, int nnz, int nb) {
    __shared__ int hist[NBMAX];
    for (int b = threadIdx.x; b < nb; b += 256) hist[b] = 0;
    __syncthreads();
    const int c0 = blockIdx.x * CHUNK;
    for (int i = threadIdx.x; i < CHUNK; i += 256) {
        int e = c0 + i;
        if (e < nnz) atomicAdd(&hist[rows[e] >> BSHIFT], 1);
    }
    __syncthreads();
    for (int b = threadIdx.x; b < nb; b += 256)
        if (hist[b]) atomicAdd(&bhist[b], hist[b]);
}

// Single block: exclusive-scan bucket hist -> bbase & gcur; rp[n_nodes]=nnz.
__global__ __launch_bounds__(1024) void bucketscan_kernel(
        const int* __restrict__ bhist, int* __restrict__ bbase,
        int* __restrict__ gcur, int* __restrict__ rp,
        int nb, int nnz, int n_nodes) {
    __shared__ int sh[1024];
    int v = (threadIdx.x < nb) ? bhist[threadIdx.x] : 0;
    sh[threadIdx.x] = v;
    __syncthreads();
    for (int off = 1; off < 1024; off <<= 1) {
        int t = (threadIdx.x >= off) ? sh[threadIdx.x - off] : 0;
        __syncthreads();
        sh[threadIdx.x] += t;
        __syncthreads();
    }
    if (threadIdx.x < nb) {
        int excl = sh[threadIdx.x] - v;
        bbase[threadIdx.x] = excl;
        gcur[threadIdx.x]  = excl;
    }
    if (threadIdx.x == 0) { bbase[nb] = nnz; rp[n_nodes] = nnz; }
}

// Phase 1: bin edges by bucket. Payload {(row_low<<COLBITS)|col, val_bits}.
__global__ __launch_bounds__(256) void binscatter_kernel(
        const int* __restrict__ rows, const int* __restrict__ cols,
        const float* __restrict__ vals, int* __restrict__ gcur,
        int2* __restrict__ bin, int nnz, int nb) {
    __shared__ int hist[NBMAX];
    __shared__ int base[NBMAX];
    __shared__ int cur[NBMAX];
    const int c0 = blockIdx.x * CHUNK;
    for (int b = threadIdx.x; b < nb; b += 256) { hist[b] = 0; cur[b] = 0; }
    __syncthreads();
    for (int i = threadIdx.x; i < CHUNK; i += 256) {
        int e = c0 + i;
        if (e < nnz) atomicAdd(&hist[rows[e] >> BSHIFT], 1);
    }
    __syncthreads();
    for (int b = threadIdx.x; b < nb; b += 256)
        if (hist[b]) base[b] = atomicAdd(&gcur[b], hist[b]);
    __syncthreads();
    for (int i = threadIdx.x; i < CHUNK; i += 256) {
        int e = c0 + i;
        if (e >= nnz) break;
        int r = rows[e];
        int b = r >> BSHIFT;
        int k = atomicAdd(&cur[b], 1);
        bin[base[b] + k] = make_int2(((r & (BROWS - 1)) << COLBITS) | cols[e],
                                     __float_as_int(vals[e]));
    }
}

// Phase 2 (one WG per bucket): count rows in LDS, scan, WRITE rp for this
// bucket, then scatter edges into row order. No global per-row histogram.
__global__ __launch_bounds__(256) void finscatter_kernel(
        const int2* __restrict__ bin, const int* __restrict__ bbase,
        int* __restrict__ rp, int2* __restrict__ sce, int n_nodes) {
    __shared__ int cnt[BROWS];
    __shared__ int sh[BROWS];
    __shared__ int cur[BROWS];
    const int row0 = blockIdx.x << BSHIFT;
    const int tid = threadIdx.x;
    cnt[tid] = 0;
    __syncthreads();
    const int bb = bbase[blockIdx.x];
    const int be = bbase[blockIdx.x + 1];
    for (int p = bb + tid; p < be; p += 256)
        atomicAdd(&cnt[bin[p].x >> COLBITS], 1);
    __syncthreads();
    int v = cnt[tid];
    sh[tid] = v;
    __syncthreads();
    for (int off = 1; off < 256; off <<= 1) {
        int t = (tid >= off) ? sh[tid - off] : 0;
        __syncthreads();
        sh[tid] += t;
        __syncthreads();
    }
    int excl = sh[tid] - v;
    cur[tid] = excl;
    if (row0 + tid < n_nodes) rp[row0 + tid] = bb + excl;   // coalesced rp build
    __syncthreads();
    for (int p = bb + tid; p < be; p += 256) {
        int2 e = bin[p];
        int rl = e.x >> COLBITS;
        int k = atomicAdd(&cur[rl], 1);
        sce[bb + k] = make_int2(e.x & ((1 << COLBITS) - 1), e.y);
    }
}

// One wave per output row, lane = dim. fp16 gathers (2 B/lane), fp32 accum,
// 8-deep batched loads into 4 rotating accumulators.
__global__ __launch_bounds__(256) void spmm_h_kernel(
        const int* __restrict__ rp, const int2* __restrict__ sce,
        const __half* __restrict__ xin, __half* __restrict__ xnxt,
        int n_nodes) {
    int wid = (int)(((long long)blockIdx.x * blockDim.x + threadIdx.x) >> 6);
    int lane = threadIdx.x & 63;
    if (wid >= n_nodes) return;
    int beg = __builtin_amdgcn_readfirstlane(rp[wid]);
    int end = __builtin_amdgcn_readfirstlane(rp[wid + 1]);
    const unsigned long long* __restrict__ sceq = (const unsigned long long*)sce;
    float s0 = 0.f, s1 = 0.f, s2 = 0.f, s3 = 0.f;
    int p = beg;
    for (; p + 8 <= end; p += 8) {
        unsigned long long u0 = __builtin_nontemporal_load(sceq + p + 0);
        unsigned long long u1 = __builtin_nontemporal_load(sceq + p + 1);
        unsigned long long u2 = __builtin_nontemporal_load(sceq + p + 2);
        unsigned long long u3 = __builtin_nontemporal_load(sceq + p + 3);
        unsigned long long u4 = __builtin_nontemporal_load(sceq + p + 4);
        unsigned long long u5 = __builtin_nontemporal_load(sceq + p + 5);
        unsigned long long u6 = __builtin_nontemporal_load(sceq + p + 6);
        unsigned long long u7 = __builtin_nontemporal_load(sceq + p + 7);
        float g0 = __half2float(xin[((int)(unsigned)u0) * EMB_C + lane]);
        float g1 = __half2float(xin[((int)(unsigned)u1) * EMB_C + lane]);
        float g2 = __half2float(xin[((int)(unsigned)u2) * EMB_C + lane]);
        float g3 = __half2float(xin[((int)(unsigned)u3) * EMB_C + lane]);
        float g4 = __half2float(xin[((int)(unsigned)u4) * EMB_C + lane]);
        float g5 = __half2float(xin[((int)(unsigned)u5) * EMB_C + lane]);
        float g6 = __half2float(xin[((int)(unsigned)u6) * EMB_C + lane]);
        float g7 = __half2float(xin[((int)(unsigned)u7) * EMB_C + lane]);
        s0 = fmaf(__int_as_float((int)(u0 >> 32)), g0, s0);
        s1 = fmaf(__int_as_float((int)(u1 >> 32)), g1, s1);
        s2 = fmaf(__int_as_float((int)(u2 >> 32)), g2, s2);
        s3 = fmaf(__int_as_float((int)(u3 >> 32)), g3, s3);
        s0 = fmaf(__int_as_float((int)(u4 >> 32)), g4, s0);
        s1 = fmaf(__int_as_float((int)(u5 >> 32)), g5, s1);
        s2 = fmaf(__int_as_float((int)(u6 >> 32)), g6, s2);
        s3 = fmaf(__int_as_float((int)(u7 >> 32)), g7, s3);
    }
    for (; p + 4 <= end; p += 4) {
        unsigned long long u0 = __builtin_nontemporal_load(sceq + p + 0);
        unsigned long long u1 = __builtin_nontemporal_load(sceq + p + 1);
        unsigned long long u2 = __builtin_nontemporal_load(sceq + p + 2);
        unsigned long long u3 = __builtin_nontemporal_load(sceq + p + 3);
        float g0 = __half2float(xin[((int)(unsigned)u0) * EMB_C + lane]);
        float g1 = __half2float(xin[((int)(unsigned)u1) * EMB_C + lane]);
        float g2 = __half2float(xin[((int)(unsigned)u2) * EMB_C + lane]);
        float g3 = __half2float(xin[((int)(unsigned)u3) * EMB_C + lane]);
        s0 = fmaf(__int_as_float((int)(u0 >> 32)), g0, s0);
        s1 = fmaf(__int_as_float((int)(u1 >> 32)), g1, s1);
        s2 = fmaf(__int_as_float((int)(u2 >> 32)), g2, s2);
        s3 = fmaf(__int_as_float((int)(u3 >> 32)), g3, s3);
    }
    for (; p < end; ++p) {
        unsigned long long u = __builtin_nontemporal_load(sceq + p);
        s0 = fmaf(__int_as_float((int)(u >> 32)),
                  __half2float(xin[((int)(unsigned)u) * EMB_C + lane]), s0);
    }
    float s = (s0 + s1) + (s2 + s3);
    unsigned short hs = __half_as_ushort(__float2half(s));
    __builtin_nontemporal_store(hs, (unsigned short*)(xnxt + wid * EMB_C + lane));
}

// out = 0.25 * (x0+x1+x2+x3)[row] at gathered rows (fp16 -> fp32 sum).
__global__ __launch_bounds__(256) void gather_h_kernel(
        const __half* __restrict__ p0, const __half* __restrict__ p1,
        const __half* __restrict__ p2, const __half* __restrict__ p3,
        const int* __restrict__ users, const int* __restrict__ pos,
        const int* __restrict__ neg, float* __restrict__ out,
        int batch, float scale) {
    long long gid = (long long)blockIdx.x * blockDim.x + threadIdx.x;
    long long per = (long long)batch * EMB_C;
    if (gid >= 3 * per) return;
    int which = (int)(gid / per);
    long long rem = gid - (long long)which * per;
    int b = (int)(rem >> 6);
    int d = (int)(rem & 63);
    long long row;
    if (which == 0)      row = users[b];
    else if (which == 1) row = (long long)N_USER_C + pos[b];
    else                 row = (long long)N_USER_C + neg[b];
    long long idx = row * EMB_C + d;
    out[gid] = scale * (__half2float(p0[idx]) + __half2float(p1[idx]) +
                        __half2float(p2[idx]) + __half2float(p3[idx]));
}

// ======================= fallback (atomic) kernels ========================

__global__ __launch_bounds__(256) void fill_kernel(
        const float4* __restrict__ ue, const float4* __restrict__ ie,
        float4* __restrict__ x0, float4* __restrict__ a,
        float4* __restrict__ b, long long u4, long long t4) {
    long long i = (long long)blockIdx.x * blockDim.x + threadIdx.x;
    if (i >= t4) return;
    float4 v = (i < u4) ? ue[i] : ie[i - u4];
    x0[i] = v;
    a[i] = v;
    b[i] = make_float4(0.f, 0.f, 0.f, 0.f);
}

__global__ __launch_bounds__(256) void spmm_kernel(
        const float* __restrict__ vals, const int* __restrict__ rows,
        const int* __restrict__ cols, const float* __restrict__ xin,
        float* __restrict__ xout, int nnz) {
    long long gid = (long long)blockIdx.x * blockDim.x + threadIdx.x;
    int e = (int)(gid >> 6);
    int d = (int)(gid & 63);
    if (e >= nnz) return;
    unsafeAtomicAdd(&xout[(long long)rows[e] * EMB_C + d],
                    vals[e] * xin[(long long)cols[e] * EMB_C + d]);
}

__global__ __launch_bounds__(256) void acczero_kernel(
        float4* __restrict__ acc, const float4* __restrict__ src,
        float4* __restrict__ tozero, long long n4) {
    long long i = (long long)blockIdx.x * blockDim.x + threadIdx.x;
    if (i >= n4) return;
    float4 a = acc[i], s = src[i];
    a.x += s.x; a.y += s.y; a.z += s.z; a.w += s.w;
    acc[i] = a;
    if (tozero) tozero[i] = make_float4(0.f, 0.f, 0.f, 0.f);
}

__global__ __launch_bounds__(256) void gather_f_kernel(
        const float* __restrict__ acc,
        const int* __restrict__ users, const int* __restrict__ pos,
        const int* __restrict__ neg, float* __restrict__ out,
        int batch, float scale) {
    long long gid = (long long)blockIdx.x * blockDim.x + threadIdx.x;
    long long per = (long long)batch * EMB_C;
    if (gid >= 3 * per) return;
    int which = (int)(gid / per);
    long long rem = gid - (long long)which * per;
    int b = (int)(rem >> 6);
    int d = (int)(rem & 63);
    long long row;
    if (which == 0)      row = users[b];
    else if (which == 1) row = (long long)N_USER_C + pos[b];
    else                 row = (long long)N_USER_C + neg[b];
    out[gid] = scale * acc[row * EMB_C + d];
}

// ================================ driver ==================================

extern "C" void kernel_launch(void* const* d_in, const int* in_sizes, int n_in,
                              void* d_out, int out_size, void* d_ws, size_t ws_size,
                              hipStream_t stream) {
    const float* ue    = (const float*)d_in[0];
    const float* ie    = (const float*)d_in[1];
    const float* vals  = (const float*)d_in[2];
    const int*   rows  = (const int*)d_in[3];
    const int*   cols  = (const int*)d_in[4];
    const int*   users = (const int*)d_in[5];
    const int*   pos   = (const int*)d_in[6];
    const int*   neg   = (const int*)d_in[7];
    float* out = (float*)d_out;

    const int nnz   = in_sizes[2];
    const int batch = in_sizes[5];
    const long long uelems = (long long)in_sizes[0];
    const long long total  = uelems + (long long)in_sizes[1];  // n_nodes * EMB
    const int n_nodes = (int)(total / EMB_C);
    const long long u4 = uelems / 4, t4 = total / 4;

    const int T = 256;
    const int fill_blocks = (int)((t4 + T - 1) / T);
    const int gath_blocks = (int)((3LL * batch * EMB_C + T - 1) / T);
    const int spmm_blocks = (int)(((long long)n_nodes * EMB_C + T - 1) / T);
    const int nb = (n_nodes + BROWS - 1) / BROWS;
    const int chunk_blocks = (nnz + CHUNK - 1) / CHUNK;

    // fp16 layout (bytes): x0..x3 (total*2 each) | rp(RN*4) | bhist/bbase/gcur
    // (1024*4 each) | sce (nnz*8) | bin (nnz*8)
    const long long RN = ((n_nodes + 1 + 15) / 16) * 16;
    const size_t xbytes = (size_t)total * 2;
    const size_t needH = 4 * xbytes + (size_t)(RN + 3072) * 4 + (size_t)nnz * 16;
    const bool fits = (nb <= NBMAX) && (n_nodes <= (1 << COLBITS));

    char* wb = (char*)d_ws;

    if (fits && ws_size >= needH) {
        __half* x0 = (__half*)wb;
        __half* x1 = (__half*)(wb + xbytes);
        __half* x2 = (__half*)(wb + 2 * xbytes);
        __half* x3 = (__half*)(wb + 3 * xbytes);
        int*   rp    = (int*)(wb + 4 * xbytes);
        int*   bhist = rp + RN;
        int*   bbase = bhist + 1024;
        int*   gcur  = bbase + 1024;
        int2*  sce   = (int2*)(gcur + 1024);
        int2*  bin   = sce + nnz;

        fill_h_kernel<<<fill_blocks, T, 0, stream>>>(
            (const float4*)ue, (const float4*)ie,
            (ushort4*)x0, (int4*)bhist, u4, t4, 1024 / 4);

        buckethist_kernel<<<chunk_blocks, T, 0, stream>>>(rows, bhist, nnz, nb);
        bucketscan_kernel<<<1, 1024, 0, stream>>>(bhist, bbase, gcur, rp, nb, nnz, n_nodes);
        binscatter_kernel<<<chunk_blocks, T, 0, stream>>>(rows, cols, vals, gcur, bin, nnz, nb);
        finscatter_kernel<<<nb, T, 0, stream>>>(bin, bbase, rp, sce, n_nodes);

        spmm_h_kernel<<<spmm_blocks, T, 0, stream>>>(rp, sce, x0, x1, n_nodes);
        spmm_h_kernel<<<spmm_blocks, T, 0, stream>>>(rp, sce, x1, x2, n_nodes);
        spmm_h_kernel<<<spmm_blocks, T, 0, stream>>>(rp, sce, x2, x3, n_nodes);

        gather_h_kernel<<<gath_blocks, T, 0, stream>>>(
            x0, x1, x2, x3, users, pos, neg, out, batch, 0.25f);
    } else {
        // ---- Tier C: 3-buffer fp32 atomic fallback ----
        float* cur = (float*)wb;
        float* nxt = cur + total;
        float* acc = nxt + total;
        fill_kernel<<<fill_blocks, T, 0, stream>>>(
            (const float4*)ue, (const float4*)ie,
            (float4*)cur, (float4*)acc, (float4*)nxt, u4, t4);
        const int espmm_blocks = (int)(((long long)nnz * EMB_C + T - 1) / T);
        for (int l = 0; l < 3; ++l) {
            spmm_kernel<<<espmm_blocks, T, 0, stream>>>(vals, rows, cols, cur, nxt, nnz);
            float4* tz = (l < 2) ? (float4*)cur : nullptr;
            acczero_kernel<<<fill_blocks, T, 0, stream>>>(
                (float4*)acc, (const float4*)nxt, tz, t4);
            float* t = cur; cur = nxt; nxt = t;
        }
        gather_f_kernel<<<gath_blocks, T, 0, stream>>>(
            acc, users, pos, neg, out, batch, 0.0625f);
    }
}